// Round 1
// baseline (689.835 us; speedup 1.0000x reference)
//
#include <hip/hip_runtime.h>
#include <hip/hip_fp16.h>
#include <stdint.h>

typedef _Float16 f16x8 __attribute__((ext_vector_type(8)));
typedef float f32x4 __attribute__((ext_vector_type(4)));

#define BM 128
#define BN 128
#define BK 64

// ---------- async global->LDS, 16B per lane (wave-uniform LDS base + lane*16) ----------
__device__ __forceinline__ void async_copy16(const void* g, void* l) {
  __builtin_amdgcn_global_load_lds(
      (__attribute__((address_space(1))) void*)(g),
      (__attribute__((address_space(3))) void*)(l),
      16, 0, 0);
}

// ---------- fp32 -> fp16 conversion (8 elements / thread) ----------
__global__ __launch_bounds__(256) void cvt_f32_f16(const float* __restrict__ in,
                                                   _Float16* __restrict__ out,
                                                   size_t n) {
  size_t i = ((size_t)blockIdx.x * 256 + threadIdx.x) * 8;
  if (i + 8 > n) return;
  float4 u = *(const float4*)(in + i);
  float4 v = *(const float4*)(in + i + 4);
  f16x8 h;
  h[0] = (_Float16)u.x; h[1] = (_Float16)u.y; h[2] = (_Float16)u.z; h[3] = (_Float16)u.w;
  h[4] = (_Float16)v.x; h[5] = (_Float16)v.y; h[6] = (_Float16)v.z; h[7] = (_Float16)v.w;
  *(f16x8*)(out + i) = h;
}

// ---------- GEMM: C[M,N] = A[M,K] * W[N,K]^T + bias, fp16 inputs, fp32 out ----------
// m97 recipe: 128x128 tile, BK=64, 4 waves (2x2 of 64x64), 16x16x32 f16 MFMA,
// global_load_lds width-16 staging (DIRECT) or in-register cvt fallback.
template <bool DIRECT>
__global__ __launch_bounds__(256) void gemm_f16(const _Float16* __restrict__ Ah,
                                                const _Float16* __restrict__ Wh,
                                                const float* __restrict__ Af,
                                                const float* __restrict__ Wf,
                                                const float* __restrict__ bias,
                                                float* __restrict__ C,
                                                int M, int N, int K) {
  __shared__ __attribute__((aligned(16))) _Float16 lsA[BM * BK];
  __shared__ __attribute__((aligned(16))) _Float16 lsB[BN * BK];

  const int tid  = threadIdx.x;
  const int wave = tid >> 6;
  const int lane = tid & 63;
  const int wrow = (wave >> 1) * 64;  // wave origin inside 128x128 tile
  const int wcol = (wave & 1) * 64;
  const int l16  = lane & 15;
  const int quad = lane >> 4;
  const int bm = blockIdx.y * BM;
  const int bn = blockIdx.x * BN;

  f32x4 acc[4][4];
#pragma unroll
  for (int i = 0; i < 4; ++i)
#pragma unroll
    for (int j = 0; j < 4; ++j) acc[i][j] = (f32x4){0.f, 0.f, 0.f, 0.f};

  for (int k0 = 0; k0 < K; k0 += BK) {
    // ---- stage A tile [128 x 64] and B tile [128 x 64] (halves, row-major) ----
    if constexpr (DIRECT) {
#pragma unroll
      for (int i = 0; i < 4; ++i) {
        const int basechunk = i * 256 + wave * 64;  // wave-uniform
        const int g   = basechunk + lane;           // chunk = 8 halves = 16B
        const int row = g >> 3;
        const int kc  = (g & 7) << 3;
        async_copy16(Ah + (size_t)(bm + row) * K + k0 + kc, &lsA[basechunk * 8]);
        async_copy16(Wh + (size_t)(bn + row) * K + k0 + kc, &lsB[basechunk * 8]);
      }
    } else {
#pragma unroll
      for (int i = 0; i < 4; ++i) {
        const int g   = i * 256 + tid;
        const int row = g >> 3;
        const int kc  = (g & 7) << 3;
        {
          const float* src = Af + (size_t)(bm + row) * K + k0 + kc;
          float4 u = *(const float4*)src;
          float4 v = *(const float4*)(src + 4);
          f16x8 h;
          h[0] = (_Float16)u.x; h[1] = (_Float16)u.y; h[2] = (_Float16)u.z; h[3] = (_Float16)u.w;
          h[4] = (_Float16)v.x; h[5] = (_Float16)v.y; h[6] = (_Float16)v.z; h[7] = (_Float16)v.w;
          *(f16x8*)&lsA[g * 8] = h;
        }
        {
          const float* src = Wf + (size_t)(bn + row) * K + k0 + kc;
          float4 u = *(const float4*)src;
          float4 v = *(const float4*)(src + 4);
          f16x8 h;
          h[0] = (_Float16)u.x; h[1] = (_Float16)u.y; h[2] = (_Float16)u.z; h[3] = (_Float16)u.w;
          h[4] = (_Float16)v.x; h[5] = (_Float16)v.y; h[6] = (_Float16)v.z; h[7] = (_Float16)v.w;
          *(f16x8*)&lsB[g * 8] = h;
        }
      }
    }
    __syncthreads();

    // ---- compute: 2 kk-steps of 32 over BK=64 ----
#pragma unroll
    for (int kk = 0; kk < BK; kk += 32) {
      f16x8 af[4], bf[4];
#pragma unroll
      for (int i = 0; i < 4; ++i)
        af[i] = *(const f16x8*)&lsA[(wrow + i * 16 + l16) * BK + kk + quad * 8];
#pragma unroll
      for (int j = 0; j < 4; ++j)
        bf[j] = *(const f16x8*)&lsB[(wcol + j * 16 + l16) * BK + kk + quad * 8];
#pragma unroll
      for (int i = 0; i < 4; ++i)
#pragma unroll
        for (int j = 0; j < 4; ++j)
          acc[i][j] = __builtin_amdgcn_mfma_f32_16x16x32_f16(af[i], bf[j], acc[i][j], 0, 0, 0);
    }
    __syncthreads();
  }

  // ---- epilogue: C[row=quad*4+reg][col=lane&15] per 16x16 tile, + bias ----
#pragma unroll
  for (int j = 0; j < 4; ++j) {
    const int c = bn + wcol + j * 16 + l16;
    const float bv = bias[c];
#pragma unroll
    for (int i = 0; i < 4; ++i) {
      const int r = bm + wrow + i * 16 + quad * 4;
      float* Cp = C + (size_t)r * N + c;
      f32x4 v = acc[i][j];
      Cp[0]            = v[0] + bv;
      Cp[(size_t)N]    = v[1] + bv;
      Cp[2 * (size_t)N] = v[2] + bv;
      Cp[3 * (size_t)N] = v[3] + bv;
    }
  }
}

// ---------- per-column sum / sumsq over the batch ----------
__global__ __launch_bounds__(256) void colstats(const float* __restrict__ H,
                                                float* __restrict__ sum,
                                                float* __restrict__ sumsq,
                                                int rowsPer, int D) {
  const int c = blockIdx.x * 256 + threadIdx.x;
  const size_t r0 = (size_t)blockIdx.y * rowsPer;
  const float* pH = H + r0 * D + c;
  float s = 0.f, s2 = 0.f;
  for (int r = 0; r < rowsPer; ++r) {
    float v = pH[(size_t)r * D];
    s += v;
    s2 += v * v;
  }
  atomicAdd(&sum[c], s);
  atomicAdd(&sumsq[c], s2);
}

// ---------- finalize BN affine: scale = rstd*gamma, shift = beta - mean*scale ----------
__global__ __launch_bounds__(256) void bn_finalize(const float* __restrict__ sum,
                                                   const float* __restrict__ sumsq,
                                                   const float* __restrict__ gamma,
                                                   const float* __restrict__ beta,
                                                   float* __restrict__ scale,
                                                   float* __restrict__ shift,
                                                   float invB) {
  const int c = blockIdx.x * 256 + threadIdx.x;
  float mean = sum[c] * invB;
  float var  = sumsq[c] * invB - mean * mean;
  float rstd = rsqrtf(var + 1e-5f);
  float sc = rstd * gamma[c];
  scale[c] = sc;
  shift[c] = beta[c] - mean * sc;
}

// ---------- fused BN + prior scale + sparsemax (Michelot), one wave per row ----------
__global__ __launch_bounds__(256) void bn_sparsemax(const float* H,
                                                    const float* __restrict__ P,
                                                    const float* __restrict__ scale,
                                                    const float* __restrict__ shift,
                                                    float* out, int D) {
  const int wave = threadIdx.x >> 6;
  const int lane = threadIdx.x & 63;
  const int row = blockIdx.x * 4 + wave;
  const size_t rowoff = (size_t)row * D;

  const f32x4* H4 = (const f32x4*)(H + rowoff);
  const f32x4* P4 = (const f32x4*)(P + rowoff);
  const f32x4* SC = (const f32x4*)scale;
  const f32x4* SH = (const f32x4*)shift;

  f32x4 z[4];  // D=1024: 4 float4-chunks per lane, coalesced (chunk j at j*64+lane)
  float tot = 0.f;
#pragma unroll
  for (int j = 0; j < 4; ++j) {
    const int idx = j * 64 + lane;
    f32x4 zz = P4[idx] * (H4[idx] * SC[idx] + SH[idx]);
    z[j] = zz;
    tot += zz[0] + zz[1] + zz[2] + zz[3];
  }
#pragma unroll
  for (int o = 32; o > 0; o >>= 1) tot += __shfl_xor(tot, o, 64);

  float tau = (tot - 1.0f) / (float)D;  // Michelot start: full support
  float kprev = -1.0f;
  for (int it = 0; it < 64; ++it) {
    float s = 0.f, kf = 0.f;
#pragma unroll
    for (int j = 0; j < 4; ++j)
#pragma unroll
      for (int c = 0; c < 4; ++c) {
        float zz = z[j][c];
        if (zz > tau) { s += zz; kf += 1.0f; }
      }
#pragma unroll
    for (int o = 32; o > 0; o >>= 1) {
      s  += __shfl_xor(s, o, 64);
      kf += __shfl_xor(kf, o, 64);
    }
    tau = (s - 1.0f) / kf;   // support >=1 always (max element stays)
    if (kf == kprev) break;  // support stable -> fixed point reached
    kprev = kf;
  }

  f32x4* O4 = (f32x4*)(out + rowoff);
#pragma unroll
  for (int j = 0; j < 4; ++j) {
    const int idx = j * 64 + lane;
    f32x4 o;
#pragma unroll
    for (int c = 0; c < 4; ++c) o[c] = fmaxf(z[j][c] - tau, 0.f);
    O4[idx] = o;
  }
}

extern "C" void kernel_launch(void* const* d_in, const int* in_sizes, int n_in,
                              void* d_out, int out_size, void* d_ws, size_t ws_size,
                              hipStream_t stream) {
  const float* a     = (const float*)d_in[0];
  const float* p     = (const float*)d_in[1];
  const float* W     = (const float*)d_in[2];
  const float* b     = (const float*)d_in[3];
  const float* gamma = (const float*)d_in[4];
  const float* beta  = (const float*)d_in[5];
  float* out = (float*)d_out;

  const int D = in_sizes[3];           // 1024
  const int Brows = in_sizes[0] / D;   // 32768
  const int K = D, N = D;

  // ws layout: [sum D][sumsq D][scale D][shift D] (16KB) | a_fp16 | W_fp16
  float* wsum   = (float*)d_ws;
  float* wsumsq = wsum + D;
  float* wscale = wsum + 2 * D;
  float* wshift = wsum + 3 * D;
  _Float16* Ah = (_Float16*)((char*)d_ws + 16384);
  _Float16* Wh = Ah + (size_t)Brows * D;
  const size_t need = 16384 + ((size_t)Brows * D + (size_t)D * D) * sizeof(_Float16);
  const bool direct = ws_size >= need;

  hipMemsetAsync(d_ws, 0, 2 * D * sizeof(float), stream);  // zero sum/sumsq

  if (direct) {
    const size_t na = (size_t)Brows * D;
    const size_t nw = (size_t)D * D;
    cvt_f32_f16<<<dim3((unsigned)(na / 8 / 256)), 256, 0, stream>>>(a, Ah, na);
    cvt_f32_f16<<<dim3((unsigned)(nw / 8 / 256)), 256, 0, stream>>>(W, Wh, nw);
    gemm_f16<true><<<dim3(N / BN, Brows / BM), 256, 0, stream>>>(
        Ah, Wh, nullptr, nullptr, b, out, Brows, N, K);
  } else {
    gemm_f16<false><<<dim3(N / BN, Brows / BM), 256, 0, stream>>>(
        nullptr, nullptr, a, W, b, out, Brows, N, K);
  }

  colstats<<<dim3(D / 256, 32), 256, 0, stream>>>(out, wsum, wsumsq, Brows / 32, D);
  bn_finalize<<<dim3(D / 256), 256, 0, stream>>>(wsum, wsumsq, gamma, beta, wscale, wshift,
                                                 1.0f / (float)Brows);
  bn_sparsemax<<<dim3(Brows / 4), 256, 0, stream>>>(out, p, wscale, wshift, out, D);
}

// Round 3
// 552.486 us; speedup vs baseline: 1.2486x; 1.2486x over previous
//
#include <hip/hip_runtime.h>
#include <hip/hip_fp16.h>
#include <stdint.h>

typedef _Float16 f16x8 __attribute__((ext_vector_type(8)));
typedef float f32x4 __attribute__((ext_vector_type(4)));

#define BM 128
#define BN 128
#define BK 64

// ---------- async global->LDS, 16B per lane (wave-uniform LDS base + lane*16) ----------
__device__ __forceinline__ void async_copy16(const void* g, void* l) {
  __builtin_amdgcn_global_load_lds(
      (__attribute__((address_space(1))) void*)(g),
      (__attribute__((address_space(3))) void*)(l),
      16, 0, 0);
}

// ---------- fp32 -> fp16 conversion (8 elements / thread) ----------
__global__ __launch_bounds__(256) void cvt_f32_f16(const float* __restrict__ in,
                                                   _Float16* __restrict__ out,
                                                   size_t n) {
  size_t i = ((size_t)blockIdx.x * 256 + threadIdx.x) * 8;
  if (i + 8 > n) return;
  float4 u = *(const float4*)(in + i);
  float4 v = *(const float4*)(in + i + 4);
  f16x8 h;
  h[0] = (_Float16)u.x; h[1] = (_Float16)u.y; h[2] = (_Float16)u.z; h[3] = (_Float16)u.w;
  h[4] = (_Float16)v.x; h[5] = (_Float16)v.y; h[6] = (_Float16)v.z; h[7] = (_Float16)v.w;
  *(f16x8*)(out + i) = h;
}

// ---------- GEMM: C[M,N] = A[M,K] * W[N,K]^T + bias, fp16 inputs, fp32 out ----------
// m97 recipe: 128x128 tile, BK=64, 4 waves (2x2 of 64x64), 16x16x32 f16 MFMA,
// global_load_lds width-16 staging (DIRECT) or in-register cvt fallback.
template <bool DIRECT>
__global__ __launch_bounds__(256) void gemm_f16(const _Float16* __restrict__ Ah,
                                                const _Float16* __restrict__ Wh,
                                                const float* __restrict__ Af,
                                                const float* __restrict__ Wf,
                                                const float* __restrict__ bias,
                                                float* __restrict__ C,
                                                int M, int N, int K) {
  __shared__ __attribute__((aligned(16))) _Float16 lsA[BM * BK];
  __shared__ __attribute__((aligned(16))) _Float16 lsB[BN * BK];

  const int tid  = threadIdx.x;
  const int wave = tid >> 6;
  const int lane = tid & 63;
  const int wrow = (wave >> 1) * 64;  // wave origin inside 128x128 tile
  const int wcol = (wave & 1) * 64;
  const int l16  = lane & 15;
  const int quad = lane >> 4;
  const int bm = blockIdx.y * BM;
  const int bn = blockIdx.x * BN;

  f32x4 acc[4][4];
#pragma unroll
  for (int i = 0; i < 4; ++i)
#pragma unroll
    for (int j = 0; j < 4; ++j) acc[i][j] = (f32x4){0.f, 0.f, 0.f, 0.f};

  for (int k0 = 0; k0 < K; k0 += BK) {
    // ---- stage A tile [128 x 64] and B tile [128 x 64] (halves, row-major) ----
    if constexpr (DIRECT) {
#pragma unroll
      for (int i = 0; i < 4; ++i) {
        const int basechunk = i * 256 + wave * 64;  // wave-uniform
        const int g   = basechunk + lane;           // chunk = 8 halves = 16B
        const int row = g >> 3;
        const int kc  = (g & 7) << 3;
        async_copy16(Ah + (size_t)(bm + row) * K + k0 + kc, &lsA[basechunk * 8]);
        async_copy16(Wh + (size_t)(bn + row) * K + k0 + kc, &lsB[basechunk * 8]);
      }
    } else {
#pragma unroll
      for (int i = 0; i < 4; ++i) {
        const int g   = i * 256 + tid;
        const int row = g >> 3;
        const int kc  = (g & 7) << 3;
        {
          const float* src = Af + (size_t)(bm + row) * K + k0 + kc;
          float4 u = *(const float4*)src;
          float4 v = *(const float4*)(src + 4);
          f16x8 h;
          h[0] = (_Float16)u.x; h[1] = (_Float16)u.y; h[2] = (_Float16)u.z; h[3] = (_Float16)u.w;
          h[4] = (_Float16)v.x; h[5] = (_Float16)v.y; h[6] = (_Float16)v.z; h[7] = (_Float16)v.w;
          *(f16x8*)&lsA[g * 8] = h;
        }
        {
          const float* src = Wf + (size_t)(bn + row) * K + k0 + kc;
          float4 u = *(const float4*)src;
          float4 v = *(const float4*)(src + 4);
          f16x8 h;
          h[0] = (_Float16)u.x; h[1] = (_Float16)u.y; h[2] = (_Float16)u.z; h[3] = (_Float16)u.w;
          h[4] = (_Float16)v.x; h[5] = (_Float16)v.y; h[6] = (_Float16)v.z; h[7] = (_Float16)v.w;
          *(f16x8*)&lsB[g * 8] = h;
        }
      }
    }
    __syncthreads();

    // ---- compute: 2 kk-steps of 32 over BK=64 ----
#pragma unroll
    for (int kk = 0; kk < BK; kk += 32) {
      f16x8 af[4], bf[4];
#pragma unroll
      for (int i = 0; i < 4; ++i)
        af[i] = *(const f16x8*)&lsA[(wrow + i * 16 + l16) * BK + kk + quad * 8];
#pragma unroll
      for (int j = 0; j < 4; ++j)
        bf[j] = *(const f16x8*)&lsB[(wcol + j * 16 + l16) * BK + kk + quad * 8];
#pragma unroll
      for (int i = 0; i < 4; ++i)
#pragma unroll
        for (int j = 0; j < 4; ++j)
          acc[i][j] = __builtin_amdgcn_mfma_f32_16x16x32_f16(af[i], bf[j], acc[i][j], 0, 0, 0);
    }
    __syncthreads();
  }

  // ---- epilogue: C[row=quad*4+reg][col=lane&15] per 16x16 tile, + bias ----
#pragma unroll
  for (int j = 0; j < 4; ++j) {
    const int c = bn + wcol + j * 16 + l16;
    const float bv = bias[c];
#pragma unroll
    for (int i = 0; i < 4; ++i) {
      const int r = bm + wrow + i * 16 + quad * 4;
      float* Cp = C + (size_t)r * N + c;
      f32x4 v = acc[i][j];
      Cp[0]            = v[0] + bv;
      Cp[(size_t)N]    = v[1] + bv;
      Cp[2 * (size_t)N] = v[2] + bv;
      Cp[3 * (size_t)N] = v[3] + bv;
    }
  }
}

// ---------- per-column sum / sumsq over the batch ----------
// Each block covers ALL D=1024 columns: thread t owns columns 4t..4t+3 (float4).
// Block b reduces rows [b*ROWS_PER, (b+1)*ROWS_PER), then one atomicAdd per column.
#define CS_ROWS 32
__global__ __launch_bounds__(256) void colstats(const float* __restrict__ H,
                                                float* __restrict__ sum,
                                                float* __restrict__ sumsq,
                                                int D) {
  const int c4 = threadIdx.x * 4;              // first of 4 owned columns
  const size_t r0 = (size_t)blockIdx.x * CS_ROWS;
  const f32x4* pH = (const f32x4*)(H + r0 * D + c4);
  const int stride4 = D >> 2;                  // float4s per row
  f32x4 s  = (f32x4){0.f, 0.f, 0.f, 0.f};
  f32x4 s2 = (f32x4){0.f, 0.f, 0.f, 0.f};
#pragma unroll
  for (int r = 0; r < CS_ROWS; r += 8) {
    f32x4 v0 = pH[(size_t)(r + 0) * stride4];
    f32x4 v1 = pH[(size_t)(r + 1) * stride4];
    f32x4 v2 = pH[(size_t)(r + 2) * stride4];
    f32x4 v3 = pH[(size_t)(r + 3) * stride4];
    f32x4 v4 = pH[(size_t)(r + 4) * stride4];
    f32x4 v5 = pH[(size_t)(r + 5) * stride4];
    f32x4 v6 = pH[(size_t)(r + 6) * stride4];
    f32x4 v7 = pH[(size_t)(r + 7) * stride4];
    s += v0 + v1 + v2 + v3 + v4 + v5 + v6 + v7;
    s2 += v0 * v0 + v1 * v1 + v2 * v2 + v3 * v3 + v4 * v4 + v5 * v5 + v6 * v6 + v7 * v7;
  }
#pragma unroll
  for (int c = 0; c < 4; ++c) {
    atomicAdd(&sum[c4 + c], s[c]);
    atomicAdd(&sumsq[c4 + c], s2[c]);
  }
}

// ---------- finalize BN affine: scale = rstd*gamma, shift = beta - mean*scale ----------
__global__ __launch_bounds__(256) void bn_finalize(const float* __restrict__ sum,
                                                   const float* __restrict__ sumsq,
                                                   const float* __restrict__ gamma,
                                                   const float* __restrict__ beta,
                                                   float* __restrict__ scale,
                                                   float* __restrict__ shift,
                                                   float invB) {
  const int c = blockIdx.x * 256 + threadIdx.x;
  float mean = sum[c] * invB;
  float var  = sumsq[c] * invB - mean * mean;
  float rstd = rsqrtf(var + 1e-5f);
  float sc = rstd * gamma[c];
  scale[c] = sc;
  shift[c] = beta[c] - mean * sc;
}

// ---------- fused BN + prior scale + sparsemax (Michelot), one wave per row ----------
__global__ __launch_bounds__(256) void bn_sparsemax(const float* H,
                                                    const float* __restrict__ P,
                                                    const float* __restrict__ scale,
                                                    const float* __restrict__ shift,
                                                    float* out, int D) {
  const int wave = threadIdx.x >> 6;
  const int lane = threadIdx.x & 63;
  const int row = blockIdx.x * 4 + wave;
  const size_t rowoff = (size_t)row * D;

  const f32x4* H4 = (const f32x4*)(H + rowoff);
  const f32x4* P4 = (const f32x4*)(P + rowoff);
  const f32x4* SC = (const f32x4*)scale;
  const f32x4* SH = (const f32x4*)shift;

  f32x4 z[4];  // D=1024: 4 float4-chunks per lane, coalesced (chunk j at j*64+lane)
  float tot = 0.f;
#pragma unroll
  for (int j = 0; j < 4; ++j) {
    const int idx = j * 64 + lane;
    f32x4 zz = P4[idx] * (H4[idx] * SC[idx] + SH[idx]);
    z[j] = zz;
    tot += zz[0] + zz[1] + zz[2] + zz[3];
  }
#pragma unroll
  for (int o = 32; o > 0; o >>= 1) tot += __shfl_xor(tot, o, 64);

  float tau = (tot - 1.0f) / (float)D;  // Michelot start: full support
  float kprev = -1.0f;
  for (int it = 0; it < 64; ++it) {
    float s = 0.f, kf = 0.f;
#pragma unroll
    for (int j = 0; j < 4; ++j)
#pragma unroll
      for (int c = 0; c < 4; ++c) {
        float zz = z[j][c];
        if (zz > tau) { s += zz; kf += 1.0f; }
      }
#pragma unroll
    for (int o = 32; o > 0; o >>= 1) {
      s  += __shfl_xor(s, o, 64);
      kf += __shfl_xor(kf, o, 64);
    }
    tau = (s - 1.0f) / kf;   // support >=1 always (max element stays)
    if (kf == kprev) break;  // support stable -> fixed point reached
    kprev = kf;
  }

  f32x4* O4 = (f32x4*)(out + rowoff);
#pragma unroll
  for (int j = 0; j < 4; ++j) {
    const int idx = j * 64 + lane;
    f32x4 o;
#pragma unroll
    for (int c = 0; c < 4; ++c) o[c] = fmaxf(z[j][c] - tau, 0.f);
    O4[idx] = o;
  }
}

extern "C" void kernel_launch(void* const* d_in, const int* in_sizes, int n_in,
                              void* d_out, int out_size, void* d_ws, size_t ws_size,
                              hipStream_t stream) {
  const float* a     = (const float*)d_in[0];
  const float* p     = (const float*)d_in[1];
  const float* W     = (const float*)d_in[2];
  const float* b     = (const float*)d_in[3];
  const float* gamma = (const float*)d_in[4];
  const float* beta  = (const float*)d_in[5];
  float* out = (float*)d_out;

  const int D = in_sizes[3];           // 1024
  const int Brows = in_sizes[0] / D;   // 32768
  const int K = D, N = D;

  // ws layout: [sum D][sumsq D][scale D][shift D] (16KB) | a_fp16 | W_fp16
  float* wsum   = (float*)d_ws;
  float* wsumsq = wsum + D;
  float* wscale = wsum + 2 * D;
  float* wshift = wsum + 3 * D;
  _Float16* Ah = (_Float16*)((char*)d_ws + 16384);
  _Float16* Wh = Ah + (size_t)Brows * D;
  const size_t need = 16384 + ((size_t)Brows * D + (size_t)D * D) * sizeof(_Float16);
  const bool direct = ws_size >= need;

  hipMemsetAsync(d_ws, 0, 2 * D * sizeof(float), stream);  // zero sum/sumsq

  if (direct) {
    const size_t na = (size_t)Brows * D;
    const size_t nw = (size_t)D * D;
    cvt_f32_f16<<<dim3((unsigned)(na / 8 / 256)), 256, 0, stream>>>(a, Ah, na);
    cvt_f32_f16<<<dim3((unsigned)(nw / 8 / 256)), 256, 0, stream>>>(W, Wh, nw);
    gemm_f16<true><<<dim3(N / BN, Brows / BM), 256, 0, stream>>>(
        Ah, Wh, nullptr, nullptr, b, out, Brows, N, K);
  } else {
    gemm_f16<false><<<dim3(N / BN, Brows / BM), 256, 0, stream>>>(
        nullptr, nullptr, a, W, b, out, Brows, N, K);
  }

  colstats<<<dim3(Brows / CS_ROWS), 256, 0, stream>>>(out, wsum, wsumsq, D);
  bn_finalize<<<dim3(D / 256), 256, 0, stream>>>(wsum, wsumsq, gamma, beta, wscale, wshift,
                                                 1.0f / (float)Brows);
  bn_sparsemax<<<dim3(Brows / 4), 256, 0, stream>>>(out, p, wscale, wshift, out, D);
}

// Round 4
// 464.072 us; speedup vs baseline: 1.4865x; 1.1905x over previous
//
#include <hip/hip_runtime.h>
#include <hip/hip_fp16.h>
#include <stdint.h>

typedef _Float16 f16x8 __attribute__((ext_vector_type(8)));
typedef float f32x4 __attribute__((ext_vector_type(4)));

#define BM 128
#define BN 128
#define BK 64

// ---------- async global->LDS, 16B per lane (wave-uniform LDS base + lane*16) ----------
__device__ __forceinline__ void async_copy16(const void* g, void* l) {
  __builtin_amdgcn_global_load_lds(
      (__attribute__((address_space(1))) void*)(g),
      (__attribute__((address_space(3))) void*)(l),
      16, 0, 0);
}

// ---------- fp32 -> fp16 conversion (8 elements / thread) ----------
__global__ __launch_bounds__(256) void cvt_f32_f16(const float* __restrict__ in,
                                                   _Float16* __restrict__ out,
                                                   size_t n) {
  size_t i = ((size_t)blockIdx.x * 256 + threadIdx.x) * 8;
  if (i + 8 > n) return;
  float4 u = *(const float4*)(in + i);
  float4 v = *(const float4*)(in + i + 4);
  f16x8 h;
  h[0] = (_Float16)u.x; h[1] = (_Float16)u.y; h[2] = (_Float16)u.z; h[3] = (_Float16)u.w;
  h[4] = (_Float16)v.x; h[5] = (_Float16)v.y; h[6] = (_Float16)v.z; h[7] = (_Float16)v.w;
  *(f16x8*)(out + i) = h;
}

// ---------- GEMM: C[M,N] = A[M,K] * W[N,K]^T + bias, fp16 in, fp32 out ----------
// 128x128 tile, BK=64, 4 waves, 16x16x32 f16 MFMA, global_load_lds width-16.
// LDS layout XOR-swizzled: chunk (row,kc) lives at slot row*8 + (kc ^ (row&7)),
// so fragment ds_read_b128 hits all 32 banks at the 8-words/bank floor
// (unswizzled: row stride = 128B = full bank sweep -> 16-way quad conflict).
// Epilogue also accumulates per-column sum/sumsq (BN stats) via quad-shuffle
// reduce + atomicAdd, eliminating the separate colstats pass over H.
template <bool DIRECT>
__global__ __launch_bounds__(256) void gemm_f16(const _Float16* __restrict__ Ah,
                                                const _Float16* __restrict__ Wh,
                                                const float* __restrict__ Af,
                                                const float* __restrict__ Wf,
                                                const float* __restrict__ bias,
                                                float* __restrict__ C,
                                                float* __restrict__ sum,
                                                float* __restrict__ sumsq,
                                                int M, int N, int K) {
  __shared__ __attribute__((aligned(16))) _Float16 lsA[BM * BK];
  __shared__ __attribute__((aligned(16))) _Float16 lsB[BN * BK];

  const int tid  = threadIdx.x;
  const int wave = tid >> 6;
  const int lane = tid & 63;
  const int wrow = (wave >> 1) * 64;  // wave origin inside 128x128 tile
  const int wcol = (wave & 1) * 64;
  const int l16  = lane & 15;
  const int quad = lane >> 4;
  const int bm = blockIdx.y * BM;
  const int bn = blockIdx.x * BN;

  f32x4 acc[4][4];
#pragma unroll
  for (int i = 0; i < 4; ++i)
#pragma unroll
    for (int j = 0; j < 4; ++j) acc[i][j] = (f32x4){0.f, 0.f, 0.f, 0.f};

  for (int k0 = 0; k0 < K; k0 += BK) {
    // ---- stage A tile [128 x 64] and B tile [128 x 64], XOR-swizzled ----
    if constexpr (DIRECT) {
#pragma unroll
      for (int i = 0; i < 4; ++i) {
        const int basechunk = i * 256 + wave * 64;  // wave-uniform LDS base
        const int g   = basechunk + lane;           // chunk = 8 halves = 16B
        const int row = g >> 3;
        const int kc  = ((g & 7) ^ (row & 7)) << 3; // swizzled source column
        async_copy16(Ah + (size_t)(bm + row) * K + k0 + kc, &lsA[basechunk * 8]);
        async_copy16(Wh + (size_t)(bn + row) * K + k0 + kc, &lsB[basechunk * 8]);
      }
    } else {
#pragma unroll
      for (int i = 0; i < 4; ++i) {
        const int g   = i * 256 + tid;
        const int row = g >> 3;
        const int kc  = ((g & 7) ^ (row & 7)) << 3;
        {
          const float* src = Af + (size_t)(bm + row) * K + k0 + kc;
          float4 u = *(const float4*)src;
          float4 v = *(const float4*)(src + 4);
          f16x8 h;
          h[0] = (_Float16)u.x; h[1] = (_Float16)u.y; h[2] = (_Float16)u.z; h[3] = (_Float16)u.w;
          h[4] = (_Float16)v.x; h[5] = (_Float16)v.y; h[6] = (_Float16)v.z; h[7] = (_Float16)v.w;
          *(f16x8*)&lsA[g * 8] = h;
        }
        {
          const float* src = Wf + (size_t)(bn + row) * K + k0 + kc;
          float4 u = *(const float4*)src;
          float4 v = *(const float4*)(src + 4);
          f16x8 h;
          h[0] = (_Float16)u.x; h[1] = (_Float16)u.y; h[2] = (_Float16)u.z; h[3] = (_Float16)u.w;
          h[4] = (_Float16)v.x; h[5] = (_Float16)v.y; h[6] = (_Float16)v.z; h[7] = (_Float16)v.w;
          *(f16x8*)&lsB[g * 8] = h;
        }
      }
    }
    __syncthreads();

    // ---- compute: 2 kk-steps of 32 over BK=64 ----
#pragma unroll
    for (int kk = 0; kk < BK; kk += 32) {
      f16x8 af[4], bf[4];
#pragma unroll
      for (int i = 0; i < 4; ++i) {
        const int r = wrow + i * 16 + l16;
        const int col = ((kk >> 3) + quad) ^ (l16 & 7);
        af[i] = *(const f16x8*)&lsA[r * 64 + col * 8];
      }
#pragma unroll
      for (int j = 0; j < 4; ++j) {
        const int r = wcol + j * 16 + l16;
        const int col = ((kk >> 3) + quad) ^ (l16 & 7);
        bf[j] = *(const f16x8*)&lsB[r * 64 + col * 8];
      }
#pragma unroll
      for (int i = 0; i < 4; ++i)
#pragma unroll
        for (int j = 0; j < 4; ++j)
          acc[i][j] = __builtin_amdgcn_mfma_f32_16x16x32_f16(af[i], bf[j], acc[i][j], 0, 0, 0);
    }
    __syncthreads();
  }

  // ---- epilogue: C[row=quad*4+reg][col=lane&15] + bias; fused column stats ----
#pragma unroll
  for (int j = 0; j < 4; ++j) {
    const int c = bn + wcol + j * 16 + l16;
    const float bv = bias[c];
    float s = 0.f, s2 = 0.f;
#pragma unroll
    for (int i = 0; i < 4; ++i) {
      const int r = bm + wrow + i * 16 + quad * 4;
      float* Cp = C + (size_t)r * N + c;
      f32x4 v = acc[i][j];
#pragma unroll
      for (int rr = 0; rr < 4; ++rr) {
        float val = v[rr] + bv;
        Cp[(size_t)rr * N] = val;
        s += val;
        s2 += val * val;
      }
    }
    // reduce across the 4 quads (lanes l16, l16+16, l16+32, l16+48 share column c)
    s  += __shfl_xor(s, 16, 64);  s  += __shfl_xor(s, 32, 64);
    s2 += __shfl_xor(s2, 16, 64); s2 += __shfl_xor(s2, 32, 64);
    if (quad == 0) {
      atomicAdd(&sum[c], s);
      atomicAdd(&sumsq[c], s2);
    }
  }
}

// ---------- finalize BN affine: scale = rstd*gamma, shift = beta - mean*scale ----------
__global__ __launch_bounds__(256) void bn_finalize(const float* __restrict__ sum,
                                                   const float* __restrict__ sumsq,
                                                   const float* __restrict__ gamma,
                                                   const float* __restrict__ beta,
                                                   float* __restrict__ scale,
                                                   float* __restrict__ shift,
                                                   float invB) {
  const int c = blockIdx.x * 256 + threadIdx.x;
  float mean = sum[c] * invB;
  float var  = sumsq[c] * invB - mean * mean;
  float rstd = rsqrtf(var + 1e-5f);
  float sc = rstd * gamma[c];
  scale[c] = sc;
  shift[c] = beta[c] - mean * sc;
}

// ---------- fused BN + prior scale + sparsemax (Michelot), one wave per row ----------
__global__ __launch_bounds__(256) void bn_sparsemax(const float* H,
                                                    const float* __restrict__ P,
                                                    const float* __restrict__ scale,
                                                    const float* __restrict__ shift,
                                                    float* out, int D) {
  const int wave = threadIdx.x >> 6;
  const int lane = threadIdx.x & 63;
  const int row = blockIdx.x * 4 + wave;
  const size_t rowoff = (size_t)row * D;

  const f32x4* H4 = (const f32x4*)(H + rowoff);
  const f32x4* P4 = (const f32x4*)(P + rowoff);
  const f32x4* SC = (const f32x4*)scale;
  const f32x4* SH = (const f32x4*)shift;

  f32x4 z[4];  // D=1024: 4 float4-chunks per lane, coalesced (chunk j at j*64+lane)
  float tot = 0.f;
#pragma unroll
  for (int j = 0; j < 4; ++j) {
    const int idx = j * 64 + lane;
    f32x4 zz = P4[idx] * (H4[idx] * SC[idx] + SH[idx]);
    z[j] = zz;
    tot += zz[0] + zz[1] + zz[2] + zz[3];
  }
#pragma unroll
  for (int o = 32; o > 0; o >>= 1) tot += __shfl_xor(tot, o, 64);

  float tau = (tot - 1.0f) / (float)D;  // Michelot start: full support
  float kprev = -1.0f;
  for (int it = 0; it < 64; ++it) {
    float s = 0.f, kf = 0.f;
#pragma unroll
    for (int j = 0; j < 4; ++j)
#pragma unroll
      for (int c = 0; c < 4; ++c) {
        float zz = z[j][c];
        if (zz > tau) { s += zz; kf += 1.0f; }
      }
#pragma unroll
    for (int o = 32; o > 0; o >>= 1) {
      s  += __shfl_xor(s, o, 64);
      kf += __shfl_xor(kf, o, 64);
    }
    tau = (s - 1.0f) / kf;   // support >=1 always (max element stays)
    if (kf == kprev) break;  // support stable -> fixed point reached
    kprev = kf;
  }

  f32x4* O4 = (f32x4*)(out + rowoff);
#pragma unroll
  for (int j = 0; j < 4; ++j) {
    const int idx = j * 64 + lane;
    f32x4 o;
#pragma unroll
    for (int c = 0; c < 4; ++c) o[c] = fmaxf(z[j][c] - tau, 0.f);
    O4[idx] = o;
  }
}

extern "C" void kernel_launch(void* const* d_in, const int* in_sizes, int n_in,
                              void* d_out, int out_size, void* d_ws, size_t ws_size,
                              hipStream_t stream) {
  const float* a     = (const float*)d_in[0];
  const float* p     = (const float*)d_in[1];
  const float* W     = (const float*)d_in[2];
  const float* b     = (const float*)d_in[3];
  const float* gamma = (const float*)d_in[4];
  const float* beta  = (const float*)d_in[5];
  float* out = (float*)d_out;

  const int D = in_sizes[3];           // 1024
  const int Brows = in_sizes[0] / D;   // 32768
  const int K = D, N = D;

  // ws layout: [sum D][sumsq D][scale D][shift D] (16KB) | a_fp16 | W_fp16
  float* wsum   = (float*)d_ws;
  float* wsumsq = wsum + D;
  float* wscale = wsum + 2 * D;
  float* wshift = wsum + 3 * D;
  _Float16* Ah = (_Float16*)((char*)d_ws + 16384);
  _Float16* Wh = Ah + (size_t)Brows * D;
  const size_t need = 16384 + ((size_t)Brows * D + (size_t)D * D) * sizeof(_Float16);
  const bool direct = ws_size >= need;

  hipMemsetAsync(d_ws, 0, 2 * D * sizeof(float), stream);  // zero sum/sumsq

  if (direct) {
    const size_t na = (size_t)Brows * D;
    const size_t nw = (size_t)D * D;
    cvt_f32_f16<<<dim3((unsigned)(na / 8 / 256)), 256, 0, stream>>>(a, Ah, na);
    cvt_f32_f16<<<dim3((unsigned)(nw / 8 / 256)), 256, 0, stream>>>(W, Wh, nw);
    gemm_f16<true><<<dim3(N / BN, Brows / BM), 256, 0, stream>>>(
        Ah, Wh, nullptr, nullptr, b, out, wsum, wsumsq, Brows, N, K);
  } else {
    gemm_f16<false><<<dim3(N / BN, Brows / BM), 256, 0, stream>>>(
        nullptr, nullptr, a, W, b, out, wsum, wsumsq, Brows, N, K);
  }

  bn_finalize<<<dim3(D / 256), 256, 0, stream>>>(wsum, wsumsq, gamma, beta, wscale, wshift,
                                                 1.0f / (float)Brows);
  bn_sparsemax<<<dim3(Brows / 4), 256, 0, stream>>>(out, p, wscale, wshift, out, D);
}

// Round 5
// 437.467 us; speedup vs baseline: 1.5769x; 1.0608x over previous
//
#include <hip/hip_runtime.h>
#include <hip/hip_fp16.h>
#include <stdint.h>

typedef _Float16 f16x8 __attribute__((ext_vector_type(8)));
typedef _Float16 f16x4 __attribute__((ext_vector_type(4)));
typedef float f32x4 __attribute__((ext_vector_type(4)));

#define BM 128
#define BN 128
#define BK 64

// ---------- async global->LDS, 16B per lane (wave-uniform LDS base + lane*16) ----------
__device__ __forceinline__ void async_copy16(const void* g, void* l) {
  __builtin_amdgcn_global_load_lds(
      (__attribute__((address_space(1))) void*)(g),
      (__attribute__((address_space(3))) void*)(l),
      16, 0, 0);
}

// ---------- fp32 -> fp16 conversion (8 elements / thread) ----------
__global__ __launch_bounds__(256) void cvt_f32_f16(const float* __restrict__ in,
                                                   _Float16* __restrict__ out,
                                                   size_t n) {
  size_t i = ((size_t)blockIdx.x * 256 + threadIdx.x) * 8;
  if (i + 8 > n) return;
  float4 u = *(const float4*)(in + i);
  float4 v = *(const float4*)(in + i + 4);
  f16x8 h;
  h[0] = (_Float16)u.x; h[1] = (_Float16)u.y; h[2] = (_Float16)u.z; h[3] = (_Float16)u.w;
  h[4] = (_Float16)v.x; h[5] = (_Float16)v.y; h[6] = (_Float16)v.z; h[7] = (_Float16)v.w;
  *(f16x8*)(out + i) = h;
}

// ---------- direct GEMM: H = A[M,K] * W[N,K]^T + bias; fused atomic-free stats ----------
// 128x128 tile, BK=64, 4 waves, 16x16x32 f16 MFMA, global_load_lds width-16.
// XOR-swizzled LDS (chunk (row,kc) at slot row*8 + (kc^(row&7))): conflict-free b128 reads.
// XCD swizzle: all 8 bn-tiles sharing a bm-tile land on one XCD (i%8 heuristic) for A L2 reuse.
// Stats: per-block partials to psum/psumsq[c*PS + bmTile*2 + rowHalf] — no atomics, no memset.
template <bool H16>
__global__ __launch_bounds__(256) void gemm_direct(const _Float16* __restrict__ Ah,
                                                   const _Float16* __restrict__ Wh,
                                                   const float* __restrict__ bias,
                                                   void* __restrict__ Hout,
                                                   float* __restrict__ psum,
                                                   float* __restrict__ psumsq,
                                                   int M, int N, int K) {
  __shared__ __attribute__((aligned(16))) _Float16 lsA[BM * BK];
  __shared__ __attribute__((aligned(16))) _Float16 lsB[BN * BK];

  const int tid  = threadIdx.x;
  const int wave = tid >> 6;
  const int lane = tid & 63;
  const int wrow = (wave >> 1) * 64;
  const int wcol = (wave & 1) * 64;
  const int l16  = lane & 15;
  const int quad = lane >> 4;

  // XCD-aware remap: linear id -> (bmTile, bnTile) s.t. same-bm blocks share an XCD
  const int nx = gridDim.x;                         // # bn tiles
  const int li = blockIdx.y * nx + blockIdx.x;
  const int xcd = li & 7;
  const int jj  = li >> 3;
  const int bnT = jj % nx;
  const int bmT = xcd + (jj / nx) * 8;
  const int bm = bmT * BM;
  const int bn = bnT * BN;

  f32x4 acc[4][4];
#pragma unroll
  for (int i = 0; i < 4; ++i)
#pragma unroll
    for (int j = 0; j < 4; ++j) acc[i][j] = (f32x4){0.f, 0.f, 0.f, 0.f};

  for (int k0 = 0; k0 < K; k0 += BK) {
#pragma unroll
    for (int i = 0; i < 4; ++i) {
      const int basechunk = i * 256 + wave * 64;    // wave-uniform LDS base
      const int g   = basechunk + lane;             // chunk = 8 halves = 16B
      const int row = g >> 3;
      const int kc  = ((g & 7) ^ (row & 7)) << 3;   // swizzled source column
      async_copy16(Ah + (size_t)(bm + row) * K + k0 + kc, &lsA[basechunk * 8]);
      async_copy16(Wh + (size_t)(bn + row) * K + k0 + kc, &lsB[basechunk * 8]);
    }
    __syncthreads();

#pragma unroll
    for (int kk = 0; kk < BK; kk += 32) {
      f16x8 af[4], bf[4];
#pragma unroll
      for (int i = 0; i < 4; ++i) {
        const int r = wrow + i * 16 + l16;
        const int col = ((kk >> 3) + quad) ^ (l16 & 7);
        af[i] = *(const f16x8*)&lsA[r * 64 + col * 8];
      }
#pragma unroll
      for (int j = 0; j < 4; ++j) {
        const int r = wcol + j * 16 + l16;
        const int col = ((kk >> 3) + quad) ^ (l16 & 7);
        bf[j] = *(const f16x8*)&lsB[r * 64 + col * 8];
      }
#pragma unroll
      for (int i = 0; i < 4; ++i)
#pragma unroll
        for (int j = 0; j < 4; ++j)
          acc[i][j] = __builtin_amdgcn_mfma_f32_16x16x32_f16(af[i], bf[j], acc[i][j], 0, 0, 0);
    }
    __syncthreads();
  }

  // ---- epilogue: H write (+bias) and per-column partial stats, no atomics ----
  const int PS = (M >> 7) * 2;  // slots per column: bmTiles * 2 row-halves
#pragma unroll
  for (int j = 0; j < 4; ++j) {
    const int c = bn + wcol + j * 16 + l16;
    const float bv = bias[c];
    float s = 0.f, s2 = 0.f;
#pragma unroll
    for (int i = 0; i < 4; ++i) {
      const int r = bm + wrow + i * 16 + quad * 4;
      f32x4 v = acc[i][j];
#pragma unroll
      for (int rr = 0; rr < 4; ++rr) {
        float val = v[rr] + bv;
        if constexpr (H16) {
          ((_Float16*)Hout)[(size_t)(r + rr) * N + c] = (_Float16)val;
        } else {
          ((float*)Hout)[(size_t)(r + rr) * N + c] = val;
        }
        s += val;
        s2 += val * val;
      }
    }
    s  += __shfl_xor(s, 16, 64);  s  += __shfl_xor(s, 32, 64);
    s2 += __shfl_xor(s2, 16, 64); s2 += __shfl_xor(s2, 32, 64);
    if (quad == 0) {
      const size_t slot = (size_t)c * PS + bmT * 2 + (wave >> 1);
      psum[slot] = s;
      psumsq[slot] = s2;
    }
  }
}

// ---------- fallback GEMM (fp32 inputs, in-register cvt, atomic stats) ----------
__global__ __launch_bounds__(256) void gemm_fallback(const float* __restrict__ Af,
                                                     const float* __restrict__ Wf,
                                                     const float* __restrict__ bias,
                                                     float* __restrict__ C,
                                                     float* __restrict__ sum,
                                                     float* __restrict__ sumsq,
                                                     int M, int N, int K) {
  __shared__ __attribute__((aligned(16))) _Float16 lsA[BM * BK];
  __shared__ __attribute__((aligned(16))) _Float16 lsB[BN * BK];
  const int tid  = threadIdx.x;
  const int wave = tid >> 6;
  const int lane = tid & 63;
  const int wrow = (wave >> 1) * 64;
  const int wcol = (wave & 1) * 64;
  const int l16  = lane & 15;
  const int quad = lane >> 4;
  const int bm = blockIdx.y * BM;
  const int bn = blockIdx.x * BN;

  f32x4 acc[4][4];
#pragma unroll
  for (int i = 0; i < 4; ++i)
#pragma unroll
    for (int j = 0; j < 4; ++j) acc[i][j] = (f32x4){0.f, 0.f, 0.f, 0.f};

  for (int k0 = 0; k0 < K; k0 += BK) {
#pragma unroll
    for (int i = 0; i < 4; ++i) {
      const int g   = i * 256 + tid;
      const int row = g >> 3;
      const int kc  = ((g & 7) ^ (row & 7)) << 3;
      {
        const float* src = Af + (size_t)(bm + row) * K + k0 + kc;
        float4 u = *(const float4*)src;
        float4 v = *(const float4*)(src + 4);
        f16x8 h;
        h[0] = (_Float16)u.x; h[1] = (_Float16)u.y; h[2] = (_Float16)u.z; h[3] = (_Float16)u.w;
        h[4] = (_Float16)v.x; h[5] = (_Float16)v.y; h[6] = (_Float16)v.z; h[7] = (_Float16)v.w;
        *(f16x8*)&lsA[g * 8] = h;
      }
      {
        const float* src = Wf + (size_t)(bn + row) * K + k0 + kc;
        float4 u = *(const float4*)src;
        float4 v = *(const float4*)(src + 4);
        f16x8 h;
        h[0] = (_Float16)u.x; h[1] = (_Float16)u.y; h[2] = (_Float16)u.z; h[3] = (_Float16)u.w;
        h[4] = (_Float16)v.x; h[5] = (_Float16)v.y; h[6] = (_Float16)v.z; h[7] = (_Float16)v.w;
        *(f16x8*)&lsB[g * 8] = h;
      }
    }
    __syncthreads();
#pragma unroll
    for (int kk = 0; kk < BK; kk += 32) {
      f16x8 af[4], bf[4];
#pragma unroll
      for (int i = 0; i < 4; ++i) {
        const int r = wrow + i * 16 + l16;
        const int col = ((kk >> 3) + quad) ^ (l16 & 7);
        af[i] = *(const f16x8*)&lsA[r * 64 + col * 8];
      }
#pragma unroll
      for (int j = 0; j < 4; ++j) {
        const int r = wcol + j * 16 + l16;
        const int col = ((kk >> 3) + quad) ^ (l16 & 7);
        bf[j] = *(const f16x8*)&lsB[r * 64 + col * 8];
      }
#pragma unroll
      for (int i = 0; i < 4; ++i)
#pragma unroll
        for (int j = 0; j < 4; ++j)
          acc[i][j] = __builtin_amdgcn_mfma_f32_16x16x32_f16(af[i], bf[j], acc[i][j], 0, 0, 0);
    }
    __syncthreads();
  }

#pragma unroll
  for (int j = 0; j < 4; ++j) {
    const int c = bn + wcol + j * 16 + l16;
    const float bv = bias[c];
    float s = 0.f, s2 = 0.f;
#pragma unroll
    for (int i = 0; i < 4; ++i) {
      const int r = bm + wrow + i * 16 + quad * 4;
      float* Cp = C + (size_t)r * N + c;
      f32x4 v = acc[i][j];
#pragma unroll
      for (int rr = 0; rr < 4; ++rr) {
        float val = v[rr] + bv;
        Cp[(size_t)rr * N] = val;
        s += val;
        s2 += val * val;
      }
    }
    s  += __shfl_xor(s, 16, 64);  s  += __shfl_xor(s, 32, 64);
    s2 += __shfl_xor(s2, 16, 64); s2 += __shfl_xor(s2, 32, 64);
    if (quad == 0) {
      atomicAdd(&sum[c], s);
      atomicAdd(&sumsq[c], s2);
    }
  }
}

// ---------- finalize from non-atomic partials: one wave per column ----------
__global__ __launch_bounds__(256) void bn_finalize_direct(const float* __restrict__ psum,
                                                          const float* __restrict__ psumsq,
                                                          const float* __restrict__ gamma,
                                                          const float* __restrict__ beta,
                                                          float* __restrict__ scale,
                                                          float* __restrict__ shift,
                                                          float invB, int PS) {
  const int wave = threadIdx.x >> 6;
  const int lane = threadIdx.x & 63;
  const int c = blockIdx.x * 4 + wave;
  const f32x4* ps = (const f32x4*)(psum + (size_t)c * PS);
  const f32x4* pq = (const f32x4*)(psumsq + (size_t)c * PS);
  float s = 0.f, q = 0.f;
  for (int k = lane; k < (PS >> 2); k += 64) {
    f32x4 v = ps[k]; s += v[0] + v[1] + v[2] + v[3];
    f32x4 w = pq[k]; q += w[0] + w[1] + w[2] + w[3];
  }
#pragma unroll
  for (int o = 32; o > 0; o >>= 1) {
    s += __shfl_xor(s, o, 64);
    q += __shfl_xor(q, o, 64);
  }
  if (lane == 0) {
    float mean = s * invB;
    float var  = q * invB - mean * mean;
    float rstd = rsqrtf(var + 1e-5f);
    float sc = rstd * gamma[c];
    scale[c] = sc;
    shift[c] = beta[c] - mean * sc;
  }
}

// ---------- finalize from atomic sums (fallback) ----------
__global__ __launch_bounds__(256) void bn_finalize(const float* __restrict__ sum,
                                                   const float* __restrict__ sumsq,
                                                   const float* __restrict__ gamma,
                                                   const float* __restrict__ beta,
                                                   float* __restrict__ scale,
                                                   float* __restrict__ shift,
                                                   float invB) {
  const int c = blockIdx.x * 256 + threadIdx.x;
  float mean = sum[c] * invB;
  float var  = sumsq[c] * invB - mean * mean;
  float rstd = rsqrtf(var + 1e-5f);
  float sc = rstd * gamma[c];
  scale[c] = sc;
  shift[c] = beta[c] - mean * sc;
}

// ---------- fused BN + prior scale + sparsemax (Michelot), one wave per row ----------
template <bool H16>
__global__ __launch_bounds__(256) void bn_sparsemax(const void* H,
                                                    const float* __restrict__ P,
                                                    const float* __restrict__ scale,
                                                    const float* __restrict__ shift,
                                                    float* out, int D) {
  const int wave = threadIdx.x >> 6;
  const int lane = threadIdx.x & 63;
  const int row = blockIdx.x * 4 + wave;
  const size_t rowoff = (size_t)row * D;

  const f32x4* P4 = (const f32x4*)(P + rowoff);
  const f32x4* SC = (const f32x4*)scale;
  const f32x4* SH = (const f32x4*)shift;

  f32x4 z[4];  // D=1024: 4 quad-chunks per lane, coalesced (chunk j at j*64+lane)
  float tot = 0.f;
#pragma unroll
  for (int j = 0; j < 4; ++j) {
    const int idx = j * 64 + lane;
    f32x4 hv;
    if constexpr (H16) {
      f16x4 h4 = ((const f16x4*)((const _Float16*)H + rowoff))[idx];
      hv[0] = (float)h4[0]; hv[1] = (float)h4[1]; hv[2] = (float)h4[2]; hv[3] = (float)h4[3];
    } else {
      hv = ((const f32x4*)((const float*)H + rowoff))[idx];
    }
    f32x4 zz = P4[idx] * (hv * SC[idx] + SH[idx]);
    z[j] = zz;
    tot += zz[0] + zz[1] + zz[2] + zz[3];
  }
#pragma unroll
  for (int o = 32; o > 0; o >>= 1) tot += __shfl_xor(tot, o, 64);

  float tau = (tot - 1.0f) / (float)D;  // Michelot start: full support
  float kprev = -1.0f;
  for (int it = 0; it < 64; ++it) {
    float s = 0.f, kf = 0.f;
#pragma unroll
    for (int j = 0; j < 4; ++j)
#pragma unroll
      for (int c = 0; c < 4; ++c) {
        float zz = z[j][c];
        if (zz > tau) { s += zz; kf += 1.0f; }
      }
#pragma unroll
    for (int o = 32; o > 0; o >>= 1) {
      s  += __shfl_xor(s, o, 64);
      kf += __shfl_xor(kf, o, 64);
    }
    tau = (s - 1.0f) / kf;   // support >=1 always (max element stays)
    if (kf == kprev) break;  // support stable -> fixed point reached
    kprev = kf;
  }

  f32x4* O4 = (f32x4*)(out + rowoff);
#pragma unroll
  for (int j = 0; j < 4; ++j) {
    const int idx = j * 64 + lane;
    f32x4 o;
#pragma unroll
    for (int c = 0; c < 4; ++c) o[c] = fmaxf(z[j][c] - tau, 0.f);
    O4[idx] = o;
  }
}

extern "C" void kernel_launch(void* const* d_in, const int* in_sizes, int n_in,
                              void* d_out, int out_size, void* d_ws, size_t ws_size,
                              hipStream_t stream) {
  const float* a     = (const float*)d_in[0];
  const float* p     = (const float*)d_in[1];
  const float* W     = (const float*)d_in[2];
  const float* b     = (const float*)d_in[3];
  const float* gamma = (const float*)d_in[4];
  const float* beta  = (const float*)d_in[5];
  float* out = (float*)d_out;

  const int D = in_sizes[3];           // 1024
  const int Brows = in_sizes[0] / D;   // 32768
  const int K = D, N = D;
  const size_t na = (size_t)Brows * D;
  const size_t nw = (size_t)D * D;
  const int PS = (Brows / BM) * 2;     // partial slots per column (512)

  // ws layout: [psum][psumsq][scale D][shift D] | Ah fp16 | Wh fp16 | Hh fp16
  const size_t statsB = (size_t)D * PS * sizeof(float);          // 2 MB
  float* psum   = (float*)d_ws;
  float* psumsq = (float*)((char*)d_ws + statsB);
  float* wscale = (float*)((char*)d_ws + 2 * statsB);
  float* wshift = wscale + D;
  const size_t off_Ah = 2 * statsB + 16384;
  _Float16* Ah = (_Float16*)((char*)d_ws + off_Ah);
  _Float16* Wh = Ah + na;
  _Float16* Hh = Wh + nw;
  const size_t need1 = off_Ah + (na + nw) * sizeof(_Float16);    // ~70 MB
  const size_t need2 = need1 + na * sizeof(_Float16);            // ~134 MB

  if (ws_size >= need1) {
    cvt_f32_f16<<<dim3((unsigned)(na / 8 / 256)), 256, 0, stream>>>(a, Ah, na);
    cvt_f32_f16<<<dim3((unsigned)(nw / 8 / 256)), 256, 0, stream>>>(W, Wh, nw);
    const bool h16 = ws_size >= need2;
    if (h16) {
      gemm_direct<true><<<dim3(N / BN, Brows / BM), 256, 0, stream>>>(
          Ah, Wh, b, Hh, psum, psumsq, Brows, N, K);
    } else {
      gemm_direct<false><<<dim3(N / BN, Brows / BM), 256, 0, stream>>>(
          Ah, Wh, b, out, psum, psumsq, Brows, N, K);
    }
    bn_finalize_direct<<<dim3(D / 4), 256, 0, stream>>>(psum, psumsq, gamma, beta,
                                                        wscale, wshift,
                                                        1.0f / (float)Brows, PS);
    if (h16) {
      bn_sparsemax<true><<<dim3(Brows / 4), 256, 0, stream>>>(Hh, p, wscale, wshift, out, D);
    } else {
      bn_sparsemax<false><<<dim3(Brows / 4), 256, 0, stream>>>(out, p, wscale, wshift, out, D);
    }
  } else {
    // tiny-ws fallback: atomic stats, fp32 H in d_out
    float* wsum   = (float*)d_ws;
    float* wsumsq = wsum + D;
    float* fscale = wsum + 2 * D;
    float* fshift = wsum + 3 * D;
    hipMemsetAsync(d_ws, 0, 2 * D * sizeof(float), stream);
    gemm_fallback<<<dim3(N / BN, Brows / BM), 256, 0, stream>>>(
        a, W, b, out, wsum, wsumsq, Brows, N, K);
    bn_finalize<<<dim3(D / 256), 256, 0, stream>>>(wsum, wsumsq, gamma, beta, fscale, fshift,
                                                   1.0f / (float)Brows);
    bn_sparsemax<false><<<dim3(Brows / 4), 256, 0, stream>>>(out, p, fscale, fshift, out, D);
  }
}